// Round 1
// baseline (885.013 us; speedup 1.0000x reference)
//
#include <hip/hip_runtime.h>
#include <hip/hip_bf16.h>
#include <math.h>

#define NTOK 1024
#define DPROJ 1024
#define PSTRIDE 1376   // padded proj row stride (cols: c0 0..1023, c1 1024..1279, c2 1280..1343, c3 1344..1359, pad ..1375)
#define HEADS 20003

typedef __attribute__((ext_vector_type(8))) short bf16x8;
typedef __attribute__((ext_vector_type(4))) float f32x4;

// fp32 -> bf16 round-to-nearest-even (finite inputs only)
__device__ __forceinline__ short f2bf(float f) {
    unsigned u = __float_as_uint(f);
    u += 0x7fffu + ((u >> 16) & 1u);
    return (short)(u >> 16);
}

__global__ __launch_bounds__(256) void cvt_hidden(const float* __restrict__ h,
                                                  short* __restrict__ hb, int n) {
    int i = blockIdx.x * 256 + threadIdx.x;
    if (i < n) hb[i] = f2bf(h[i]);
}

// p is [DPROJ x d] row-major; dst (pre-offset) is [d x DPROJ] bf16
__global__ __launch_bounds__(256) void transpose_p(const float* __restrict__ p,
                                                   short* __restrict__ dst, int d) {
    int i = blockIdx.x * 256 + threadIdx.x;
    if (i < DPROJ * d) {
        int k = i / d;
        int j = i - k * d;
        dst[j * DPROJ + k] = f2bf(p[i]);
    }
}

// proj = hidden @ p  via MFMA. One wave per 16x16 tile.
// A = hb [NTOK x DPROJ] row-major (m = token). B^T = pTb_c [d x DPROJ] (n = proj col).
__global__ __launch_bounds__(64) void proj_gemm(const short* __restrict__ hb,
                                                const short* __restrict__ pTb,
                                                float* __restrict__ projf,
                                                short* __restrict__ projb,
                                                int coloff) {
    int lane = threadIdx.x;
    int t0 = blockIdx.x * 16;
    int j0 = blockIdx.y * 16;
    int l16 = lane & 15, quad = lane >> 4;
    const short* aptr = hb + (t0 + l16) * DPROJ + quad * 8;
    const short* bptr = pTb + (j0 + l16) * DPROJ + quad * 8;
    f32x4 acc = {0.f, 0.f, 0.f, 0.f};
    #pragma unroll 8
    for (int k0 = 0; k0 < DPROJ; k0 += 32) {
        bf16x8 a = *(const bf16x8*)(aptr + k0);
        bf16x8 b = *(const bf16x8*)(bptr + k0);
        acc = __builtin_amdgcn_mfma_f32_16x16x32_bf16(a, b, acc, 0, 0, 0);
    }
    // C/D: col = lane&15 (proj col), row = quad*4 + r (token)
    #pragma unroll
    for (int r = 0; r < 4; ++r) {
        int row = t0 + quad * 4 + r;
        int col = coloff + j0 + l16;
        projf[row * PSTRIDE + col] = acc[r];
        projb[row * PSTRIDE + col] = f2bf(acc[r]);
    }
}

// Fused logsumexp-GEMM for one cluster.
// A = w rows (V x D, fp32, converted inline to bf16, resident in regs, read once).
// B = proj tokens (bf16, from L2). Epilogue: sum_exp per token via shfl + LDS.
template <int D>
__global__ __launch_bounds__(256) void lse_kernel(const float* __restrict__ w,
                                                  const float* __restrict__ bias,
                                                  const short* __restrict__ projb,
                                                  float* __restrict__ sumrow,
                                                  int V, int coloff) {
    constexpr int KSTEPS = (D + 31) / 32;
    __shared__ float blocksum[NTOK];
    int tid = threadIdx.x;
    for (int i = tid; i < NTOK; i += 256) blocksum[i] = 0.f;
    __syncthreads();

    int wave = tid >> 6, lane = tid & 63;
    int quad = lane >> 4, l16 = lane & 15;
    int v0 = blockIdx.x * 64 + wave * 16;

    // resident A fragments: lane holds w[v0 + l16][ks*32 + quad*8 .. +8]
    bf16x8 areg[KSTEPS];
    int va = v0 + l16;
    #pragma unroll
    for (int ks = 0; ks < KSTEPS; ++ks) {
        int k = ks * 32 + quad * 8;
        bf16x8 f;
        if (va < V && k < D) {
            const float* wp = w + (long)va * D + k;
            float4 x = *(const float4*)(wp);
            float4 y = *(const float4*)(wp + 4);
            f[0] = f2bf(x.x); f[1] = f2bf(x.y); f[2] = f2bf(x.z); f[3] = f2bf(x.w);
            f[4] = f2bf(y.x); f[5] = f2bf(y.y); f[6] = f2bf(y.z); f[7] = f2bf(y.w);
        } else {
            #pragma unroll
            for (int j = 0; j < 8; ++j) f[j] = 0;
        }
        areg[ks] = f;
    }
    // bias for this lane's C rows: v = v0 + quad*4 + r
    float bb[4];
    #pragma unroll
    for (int r = 0; r < 4; ++r) {
        int vb = v0 + quad * 4 + r;
        bb[r] = (vb < V) ? bias[vb] : -1e30f;
    }

    for (int tt = 0; tt < NTOK / 16; ++tt) {
        const short* bp = projb + (tt * 16 + l16) * PSTRIDE + coloff + quad * 8;
        f32x4 acc = {0.f, 0.f, 0.f, 0.f};
        #pragma unroll
        for (int ks = 0; ks < KSTEPS; ++ks) {
            bf16x8 b = *(const bf16x8*)(bp + ks * 32);
            acc = __builtin_amdgcn_mfma_f32_16x16x32_bf16(areg[ks], b, acc, 0, 0, 0);
        }
        // lane holds D[m = quad*4+r][n = l16]; sum exp over this lane's 4 v's
        float e = __expf(acc[0] + bb[0]) + __expf(acc[1] + bb[1]) +
                  __expf(acc[2] + bb[2]) + __expf(acc[3] + bb[3]);
        // reduce across the 4 quads (same token n)
        e += __shfl_xor(e, 16, 64);
        e += __shfl_xor(e, 32, 64);
        if (lane < 16) atomicAdd(&blocksum[tt * 16 + lane], e);
    }
    __syncthreads();
    for (int i = tid; i < NTOK; i += 256) atomicAdd(&sumrow[i], blocksum[i]);
}

// One wave per token: exact fp32 gathered logits + combine with lse's.
__global__ __launch_bounds__(256) void finalize(const int* __restrict__ target,
                                                const float* __restrict__ projf,
                                                const float* __restrict__ sums,
                                                const float* __restrict__ w0, const float* __restrict__ b0,
                                                const float* __restrict__ w1, const float* __restrict__ b1,
                                                const float* __restrict__ w2, const float* __restrict__ b2,
                                                const float* __restrict__ w3, const float* __restrict__ b3,
                                                float* __restrict__ out) {
    int wave = threadIdx.x >> 6, lane = threadIdx.x & 63;
    int row = blockIdx.x * 4 + wave;
    int t = target[row];
    int c = (t < 20000) ? 0 : (t < 40000) ? 1 : (t < 200000) ? 2 : 3;
    int col0 = (c == 0) ? t : (HEADS - c);
    const float* pr = projf + row * PSTRIDE;

    float s = 0.f;
    for (int k = lane; k < DPROJ; k += 64) s += pr[k] * w0[col0 * DPROJ + k];
    #pragma unroll
    for (int off = 32; off; off >>= 1) s += __shfl_xor(s, off, 64);
    float hl = s + b0[col0];
    float lse0 = __logf(sums[row]);

    float res;
    if (c == 0) {
        res = lse0 - hl;
    } else {
        const float* wc; const float* bc; int d, coloff, l;
        if (c == 1)      { wc = w1; bc = b1; d = 256; coloff = 1024; l = 20000; }
        else if (c == 2) { wc = w2; bc = b2; d = 64;  coloff = 1280; l = 40000; }
        else             { wc = w3; bc = b3; d = 16;  coloff = 1344; l = 200000; }
        int tc = t - l;
        float s2 = 0.f;
        for (int k = lane; k < d; k += 64) s2 += pr[coloff + k] * wc[tc * d + k];
        #pragma unroll
        for (int off = 32; off; off >>= 1) s2 += __shfl_xor(s2, off, 64);
        float tl = s2 + bc[tc];
        float lsec = __logf(sums[c * NTOK + row]);
        res = lse0 - hl + lsec - tl;
    }
    if (lane == 0) out[row] = res;
}

// workspace layout (bytes)
#define HB_OFF    0ull                          // 1024*1024 bf16 = 2 MB
#define PTB_OFF   (HB_OFF + 1024ull*1024*2)     // 1360*1024 bf16
#define PROJF_OFF (PTB_OFF + 1360ull*1024*2)    // 1024*1376 f32
#define PROJB_OFF (PROJF_OFF + 1024ull*1376*4)  // 1024*1376 bf16
#define SUM_OFF   (PROJB_OFF + 1024ull*1376*2)  // 4*1024 f32

extern "C" void kernel_launch(void* const* d_in, const int* in_sizes, int n_in,
                              void* d_out, int out_size, void* d_ws, size_t ws_size,
                              hipStream_t stream) {
    const float* hidden = (const float*)d_in[0];
    const int*   target = (const int*)d_in[1];
    const float* w0 = (const float*)d_in[2];
    const float* b0 = (const float*)d_in[3];
    const float* p0 = (const float*)d_in[4];
    const float* w1 = (const float*)d_in[5];
    const float* b1 = (const float*)d_in[6];
    const float* p1 = (const float*)d_in[7];
    const float* w2 = (const float*)d_in[8];
    const float* b2 = (const float*)d_in[9];
    const float* p2 = (const float*)d_in[10];
    const float* w3 = (const float*)d_in[11];
    const float* b3 = (const float*)d_in[12];
    const float* p3 = (const float*)d_in[13];

    char* ws = (char*)d_ws;
    short* hb    = (short*)(ws + HB_OFF);
    short* pTb   = (short*)(ws + PTB_OFF);
    float* projf = (float*)(ws + PROJF_OFF);
    short* projb = (short*)(ws + PROJB_OFF);
    float* sums  = (float*)(ws + SUM_OFF);

    cvt_hidden<<<4096, 256, 0, stream>>>(hidden, hb, 1024 * 1024);
    transpose_p<<<(1024 * 1024 + 255) / 256, 256, 0, stream>>>(p0, pTb + 0, 1024);
    transpose_p<<<(1024 * 256 + 255) / 256, 256, 0, stream>>>(p1, pTb + 1024 * 1024, 256);
    transpose_p<<<(1024 * 64 + 255) / 256, 256, 0, stream>>>(p2, pTb + 1280 * 1024, 64);
    transpose_p<<<(1024 * 16 + 255) / 256, 256, 0, stream>>>(p3, pTb + 1344 * 1024, 16);
    hipMemsetAsync(ws + SUM_OFF, 0, 4 * NTOK * sizeof(float), stream);

    proj_gemm<<<dim3(64, 64), 64, 0, stream>>>(hb, pTb + 0,           projf, projb, 0);
    proj_gemm<<<dim3(64, 16), 64, 0, stream>>>(hb, pTb + 1024 * 1024, projf, projb, 1024);
    proj_gemm<<<dim3(64, 4),  64, 0, stream>>>(hb, pTb + 1280 * 1024, projf, projb, 1280);
    proj_gemm<<<dim3(64, 1),  64, 0, stream>>>(hb, pTb + 1344 * 1024, projf, projb, 1344);

    lse_kernel<1024><<<313, 256, 0, stream>>>(w0, b0, projb, sums + 0 * NTOK, 20003, 0);
    lse_kernel<256> <<<313, 256, 0, stream>>>(w1, b1, projb, sums + 1 * NTOK, 20000, 1024);
    lse_kernel<64>  <<<2500, 256, 0, stream>>>(w2, b2, projb, sums + 2 * NTOK, 160000, 1280);
    lse_kernel<16>  <<<1059, 256, 0, stream>>>(w3, b3, projb, sums + 3 * NTOK, 67735, 1344);

    finalize<<<256, 256, 0, stream>>>(target, projf, sums,
                                      w0, b0, w1, b1, w2, b2, w3, b3, (float*)d_out);
}

// Round 2
// 631.273 us; speedup vs baseline: 1.4020x; 1.4020x over previous
//
#include <hip/hip_runtime.h>
#include <hip/hip_bf16.h>
#include <math.h>

#define NTOK 1024
#define DPROJ 1024
#define PSTRIDE 1376
#define HEADS 20003

typedef __attribute__((ext_vector_type(8))) short bf16x8;
typedef __attribute__((ext_vector_type(4))) float f32x4;

__device__ __forceinline__ short f2bf(float f) {
    unsigned u = __float_as_uint(f);
    u += 0x7fffu + ((u >> 16) & 1u);
    return (short)(u >> 16);
}

__global__ __launch_bounds__(256) void cvt_hidden(const float* __restrict__ h,
                                                  short* __restrict__ hb, int n) {
    int i = blockIdx.x * 256 + threadIdx.x;
    if (i < n) hb[i] = f2bf(h[i]);
}

// p is [DPROJ x d] row-major; dst is [d x DPROJ] bf16
__global__ __launch_bounds__(256) void transpose_p(const float* __restrict__ p,
                                                   short* __restrict__ dst, int d) {
    int i = blockIdx.x * 256 + threadIdx.x;
    if (i < DPROJ * d) {
        int k = i / d;
        int j = i - k * d;
        dst[j * DPROJ + k] = f2bf(p[i]);
    }
}

// proj = hidden @ p via MFMA; writes fp32 (finalize) and bf16 packed-fragment layout (lse).
// packed layout per cluster: chunk index (tt*KS + ks)*64 + quad*16 + l16  holds
// proj[token = tt*16+l16][col = coloff + ks*32 + quad*8 .. +8] as 8 bf16.
__global__ __launch_bounds__(64) void proj_gemm(const short* __restrict__ hb,
                                                const short* __restrict__ pTbc,
                                                float* __restrict__ projf,
                                                short* __restrict__ packedc,
                                                int coloff, int KS) {
    int lane = threadIdx.x;
    int t0 = blockIdx.x * 16;
    int j0 = blockIdx.y * 16;           // cluster-relative col tile
    int l16 = lane & 15, quad = lane >> 4;
    const short* aptr = hb + (t0 + l16) * DPROJ + quad * 8;
    const short* bptr = pTbc + (j0 + l16) * DPROJ + quad * 8;
    f32x4 acc = {0.f, 0.f, 0.f, 0.f};
    #pragma unroll 8
    for (int k0 = 0; k0 < DPROJ; k0 += 32) {
        bf16x8 a = *(const bf16x8*)(aptr + k0);
        bf16x8 b = *(const bf16x8*)(bptr + k0);
        acc = __builtin_amdgcn_mfma_f32_16x16x32_bf16(a, b, acc, 0, 0, 0);
    }
    #pragma unroll
    for (int r = 0; r < 4; ++r) {
        int token = t0 + quad * 4 + r;
        int kk = j0 + l16;
        projf[token * PSTRIDE + coloff + kk] = acc[r];
        int tt = token >> 4, l16p = token & 15;
        int ks = kk >> 5, within = kk & 31;
        int chunk = (tt * KS + ks) * 64 + (within >> 3) * 16 + l16p;
        packedc[chunk * 8 + (within & 7)] = f2bf(acc[r]);
    }
}

// ---------------- head: KSTEPS=32, 4 waves/block, LDS-staged B, reg-prefetch dbuf ----
__global__ __launch_bounds__(256) void lse_head(const float* __restrict__ w,
                                                const float* __restrict__ bias,
                                                const short* __restrict__ packed0,
                                                float* __restrict__ sumrow, int V) {
    constexpr int KS = 32;
    __shared__ __align__(16) short sbuf[2][KS * 64 * 8];   // 2 x 32 KB
    __shared__ float bsum[4][NTOK];                         // 16 KB
    int tid = threadIdx.x;
    int wave = tid >> 6, lane = tid & 63;
    int quad = lane >> 4, l16 = lane & 15;
    int v0 = blockIdx.x * 64 + wave * 16;

    // resident A fragments
    bf16x8 areg[KS];
    int va = v0 + l16;
    #pragma unroll
    for (int ks = 0; ks < KS; ++ks) {
        int k = ks * 32 + quad * 8;
        bf16x8 f;
        if (va < V) {
            const float* wp = w + (long)va * DPROJ + k;
            float4 x = *(const float4*)(wp);
            float4 y = *(const float4*)(wp + 4);
            f[0]=f2bf(x.x); f[1]=f2bf(x.y); f[2]=f2bf(x.z); f[3]=f2bf(x.w);
            f[4]=f2bf(y.x); f[5]=f2bf(y.y); f[6]=f2bf(y.z); f[7]=f2bf(y.w);
        } else {
            #pragma unroll
            for (int j = 0; j < 8; ++j) f[j] = 0;
        }
        areg[ks] = f;
    }
    float bb[4];
    #pragma unroll
    for (int r = 0; r < 4; ++r) {
        int vb = v0 + quad * 4 + r;
        bb[r] = (vb < V) ? bias[vb] : -1e30f;
    }

    const bf16x8* gsrc = (const bf16x8*)packed0;
    bf16x8 pf[8];
    // stage tile 0
    #pragma unroll
    for (int i = 0; i < 8; ++i) pf[i] = gsrc[tid + i * 256];
    {
        bf16x8* d = (bf16x8*)sbuf[0];
        #pragma unroll
        for (int i = 0; i < 8; ++i) d[tid + i * 256] = pf[i];
    }
    __syncthreads();

    for (int tt = 0; tt < 64; ++tt) {
        if (tt < 63) {
            const bf16x8* s = gsrc + (size_t)(tt + 1) * 2048;
            #pragma unroll
            for (int i = 0; i < 8; ++i) pf[i] = s[tid + i * 256];
        }
        const short* sb = sbuf[tt & 1];
        f32x4 acc = {0.f, 0.f, 0.f, 0.f};
        #pragma unroll
        for (int ks = 0; ks < KS; ++ks) {
            bf16x8 b = *(const bf16x8*)(sb + (ks * 64 + lane) * 8);
            acc = __builtin_amdgcn_mfma_f32_16x16x32_bf16(areg[ks], b, acc, 0, 0, 0);
        }
        float e = __expf(acc[0] + bb[0]) + __expf(acc[1] + bb[1]) +
                  __expf(acc[2] + bb[2]) + __expf(acc[3] + bb[3]);
        e += __shfl_xor(e, 16, 64);
        e += __shfl_xor(e, 32, 64);
        if (lane < 16) bsum[wave][tt * 16 + lane] = e;
        if (tt < 63) {
            bf16x8* d = (bf16x8*)sbuf[(tt + 1) & 1];
            #pragma unroll
            for (int i = 0; i < 8; ++i) d[tid + i * 256] = pf[i];
        }
        __syncthreads();
    }
    for (int i = tid; i < NTOK; i += 256) {
        float s = bsum[0][i] + bsum[1][i] + bsum[2][i] + bsum[3][i];
        atomicAdd(&sumrow[i], s);
    }
}

// ---------------- tails: single-wave blocks, VTILES v-tiles resident, coalesced B ----
template <int KS, int VT>
__global__ __launch_bounds__(64) void lse_tail(const float* __restrict__ w,
                                               const float* __restrict__ bias,
                                               const short* __restrict__ packedc,
                                               float* __restrict__ sumrow,
                                               int V, int D) {
    __shared__ float blocksum[NTOK];
    int lane = threadIdx.x;
    int quad = lane >> 4, l16 = lane & 15;
    int v0 = blockIdx.x * (16 * VT);

    bf16x8 areg[VT][KS];
    float bb[VT][4];
    #pragma unroll
    for (int vt = 0; vt < VT; ++vt) {
        int va = v0 + vt * 16 + l16;
        #pragma unroll
        for (int ks = 0; ks < KS; ++ks) {
            int k = ks * 32 + quad * 8;
            bf16x8 f;
            if (va < V && k < D) {
                const float* wp = w + (long)va * D + k;
                float4 x = *(const float4*)(wp);
                float4 y = *(const float4*)(wp + 4);
                f[0]=f2bf(x.x); f[1]=f2bf(x.y); f[2]=f2bf(x.z); f[3]=f2bf(x.w);
                f[4]=f2bf(y.x); f[5]=f2bf(y.y); f[6]=f2bf(y.z); f[7]=f2bf(y.w);
            } else {
                #pragma unroll
                for (int j = 0; j < 8; ++j) f[j] = 0;
            }
            areg[vt][ks] = f;
        }
        #pragma unroll
        for (int r = 0; r < 4; ++r) {
            int vb = v0 + vt * 16 + quad * 4 + r;
            bb[vt][r] = (vb < V) ? bias[vb] : -1e30f;
        }
    }

    for (int tt = 0; tt < 64; ++tt) {
        const short* bp = packedc + ((size_t)tt * KS * 64 + lane) * 8;
        bf16x8 breg[KS];
        #pragma unroll
        for (int ks = 0; ks < KS; ++ks)
            breg[ks] = *(const bf16x8*)(bp + ks * 512);
        float e = 0.f;
        #pragma unroll
        for (int vt = 0; vt < VT; ++vt) {
            f32x4 acc = {0.f, 0.f, 0.f, 0.f};
            #pragma unroll
            for (int ks = 0; ks < KS; ++ks)
                acc = __builtin_amdgcn_mfma_f32_16x16x32_bf16(areg[vt][ks], breg[ks], acc, 0, 0, 0);
            e += __expf(acc[0] + bb[vt][0]) + __expf(acc[1] + bb[vt][1]) +
                 __expf(acc[2] + bb[vt][2]) + __expf(acc[3] + bb[vt][3]);
        }
        e += __shfl_xor(e, 16, 64);
        e += __shfl_xor(e, 32, 64);
        if (lane < 16) blocksum[tt * 16 + lane] = e;   // each entry written exactly once
    }
    for (int i = lane; i < NTOK; i += 64)
        atomicAdd(&sumrow[i], blocksum[i]);
}

__global__ __launch_bounds__(256) void finalize(const int* __restrict__ target,
                                                const float* __restrict__ projf,
                                                const float* __restrict__ sums,
                                                const float* __restrict__ w0, const float* __restrict__ b0,
                                                const float* __restrict__ w1, const float* __restrict__ b1,
                                                const float* __restrict__ w2, const float* __restrict__ b2,
                                                const float* __restrict__ w3, const float* __restrict__ b3,
                                                float* __restrict__ out) {
    int wave = threadIdx.x >> 6, lane = threadIdx.x & 63;
    int row = blockIdx.x * 4 + wave;
    int t = target[row];
    int c = (t < 20000) ? 0 : (t < 40000) ? 1 : (t < 200000) ? 2 : 3;
    int col0 = (c == 0) ? t : (HEADS - c);
    const float* pr = projf + row * PSTRIDE;

    float s = 0.f;
    for (int k = lane; k < DPROJ; k += 64) s += pr[k] * w0[col0 * DPROJ + k];
    #pragma unroll
    for (int off = 32; off; off >>= 1) s += __shfl_xor(s, off, 64);
    float hl = s + b0[col0];
    float lse0 = __logf(sums[row]);

    float res;
    if (c == 0) {
        res = lse0 - hl;
    } else {
        const float* wc; const float* bc; int d, coloff, l;
        if (c == 1)      { wc = w1; bc = b1; d = 256; coloff = 1024; l = 20000; }
        else if (c == 2) { wc = w2; bc = b2; d = 64;  coloff = 1280; l = 40000; }
        else             { wc = w3; bc = b3; d = 16;  coloff = 1344; l = 200000; }
        int tc = t - l;
        float s2 = 0.f;
        for (int k = lane; k < d; k += 64) s2 += pr[coloff + k] * wc[tc * d + k];
        #pragma unroll
        for (int off = 32; off; off >>= 1) s2 += __shfl_xor(s2, off, 64);
        float tl = s2 + bc[tc];
        float lsec = __logf(sums[c * NTOK + row]);
        res = lse0 - hl + lsec - tl;
    }
    if (lane == 0) out[row] = res;
}

// workspace layout (bytes)
#define HB_OFF    0ull                            // 1024*1024 bf16 = 2 MB
#define PTB_OFF   (HB_OFF + 1024ull*1024*2)       // 1360*1024 bf16
#define PROJF_OFF (PTB_OFF + 1360ull*1024*2)      // 1024*1376 f32
#define PACK_OFF  (PROJF_OFF + 1024ull*1376*4)    // 1409024 bf16
#define SUM_OFF   (PACK_OFF + 1409024ull*2)       // 4*1024 f32

extern "C" void kernel_launch(void* const* d_in, const int* in_sizes, int n_in,
                              void* d_out, int out_size, void* d_ws, size_t ws_size,
                              hipStream_t stream) {
    const float* hidden = (const float*)d_in[0];
    const int*   target = (const int*)d_in[1];
    const float* w0 = (const float*)d_in[2];
    const float* b0 = (const float*)d_in[3];
    const float* p0 = (const float*)d_in[4];
    const float* w1 = (const float*)d_in[5];
    const float* b1 = (const float*)d_in[6];
    const float* p1 = (const float*)d_in[7];
    const float* w2 = (const float*)d_in[8];
    const float* b2 = (const float*)d_in[9];
    const float* p2 = (const float*)d_in[10];
    const float* w3 = (const float*)d_in[11];
    const float* b3 = (const float*)d_in[12];
    const float* p3 = (const float*)d_in[13];

    char* ws = (char*)d_ws;
    short* hb    = (short*)(ws + HB_OFF);
    short* pTb   = (short*)(ws + PTB_OFF);
    float* projf = (float*)(ws + PROJF_OFF);
    short* pk    = (short*)(ws + PACK_OFF);
    float* sums  = (float*)(ws + SUM_OFF);
    short* pk0 = pk;
    short* pk1 = pk0 + 64 * 32 * 64 * 8;   // 1048576
    short* pk2 = pk1 + 64 * 8 * 64 * 8;    //  262144
    short* pk3 = pk2 + 64 * 2 * 64 * 8;    //   65536

    cvt_hidden<<<4096, 256, 0, stream>>>(hidden, hb, 1024 * 1024);
    transpose_p<<<(1024 * 1024 + 255) / 256, 256, 0, stream>>>(p0, pTb + 0, 1024);
    transpose_p<<<(1024 * 256 + 255) / 256, 256, 0, stream>>>(p1, pTb + 1024 * 1024, 256);
    transpose_p<<<(1024 * 64 + 255) / 256, 256, 0, stream>>>(p2, pTb + 1280 * 1024, 64);
    transpose_p<<<(1024 * 16 + 255) / 256, 256, 0, stream>>>(p3, pTb + 1344 * 1024, 16);
    hipMemsetAsync(ws + PACK_OFF, 0, 1409024 * 2, stream);     // zero (c3 k-pad)
    hipMemsetAsync(ws + SUM_OFF, 0, 4 * NTOK * sizeof(float), stream);

    proj_gemm<<<dim3(64, 64), 64, 0, stream>>>(hb, pTb + 0,           projf, pk0, 0,    32);
    proj_gemm<<<dim3(64, 16), 64, 0, stream>>>(hb, pTb + 1024 * 1024, projf, pk1, 1024, 8);
    proj_gemm<<<dim3(64, 4),  64, 0, stream>>>(hb, pTb + 1280 * 1024, projf, pk2, 1280, 2);
    proj_gemm<<<dim3(64, 1),  64, 0, stream>>>(hb, pTb + 1344 * 1024, projf, pk3, 1344, 1);

    lse_head<<<313, 256, 0, stream>>>(w0, b0, pk0, sums + 0 * NTOK, HEADS);
    lse_tail<8, 2><<<625, 64, 0, stream>>>(w1, b1, pk1, sums + 1 * NTOK, 20000, 256);
    lse_tail<2, 4><<<2500, 64, 0, stream>>>(w2, b2, pk2, sums + 2 * NTOK, 160000, 64);
    lse_tail<1, 4><<<1059, 64, 0, stream>>>(w3, b3, pk3, sums + 3 * NTOK, 67735, 16);

    finalize<<<256, 256, 0, stream>>>(target, projf, sums,
                                      w0, b0, w1, b1, w2, b2, w3, b3, (float*)d_out);
}